// Round 4
// baseline (579.099 us; speedup 1.0000x reference)
//
#include <hip/hip_runtime.h>

// Problem constants (match reference): K=4, B=4096, T=32, D=128
constexpr int K = 4;
constexpr int B = 4096;   // power of two: kb>>12 = k
constexpr int T = 32;
constexpr int D = 128;
constexpr int TT = T * T;   // 1024 pairs per anchor
constexpr int TD = T * D;   // 4096 floats per anchor's nbr_embed

typedef float f4 __attribute__((ext_vector_type(4)));

__device__ __forceinline__ float dot4(f4 a, f4 b) {
    return a.x * b.x + a.y * b.y + a.z * b.z + a.w * b.w;
}

__device__ __forceinline__ float hreduce32(float p) {
    #pragma unroll
    for (int m = 16; m >= 1; m >>= 1) p += __shfl_xor(p, m, 64);
    return p;
}

struct __align__(16) WaveSh { float nsim[T]; };

// ---------------------------------------------------------------------------
// R4 PROBE: four structural theories (sync, read locality, XCD affinity,
// write-stream count) all neutral at dur ~460-472. The inference "kernel =
// dur - fill = ~165us" was never verified; competing model: kernel is already
// at its ~80us write floor and the residual is harness reset()/launch-gap
// overhead. All kernels here are idempotent (pure deterministic writes), so
// launching the WHOLE PIPELINE TWICE adds exactly one kernel-time K:
//   dur -> ~635  => K~165, real headroom, old model right
//   dur -> ~555  => K~85, kernel at write roofline, residual is fixed
// Kernels below are byte-identical to R3.
// ---------------------------------------------------------------------------

__global__ __launch_bounds__(256) void gather_kernel(
    const float* __restrict__ semb,     // [K,B,D]
    const int*   __restrict__ slabels,  // [K,B]
    const int*   __restrict__ topk,     // [K,B,T]
    float*       __restrict__ nbr,      // [K,B,T,D]
    float*       __restrict__ ws_nsim,  // [K,B,T]
    unsigned*    __restrict__ ws_mask)  // [K,B]
{
    const int tid  = threadIdx.x;
    const int wid  = tid >> 6;
    const int l    = tid & 63;
    const int half = l >> 5;
    const int d4   = l & 31;

    const int kb = blockIdx.x * 4 + wid;
    const int k  = kb >> 12;

    __shared__ WaveSh sh[4];
    WaveSh& w = sh[wid];

    const int my_label = slabels[kb];
    const int idx_l    = topk[kb * T + d4];
    const int same_l   = (slabels[(k << 12) + idx_l] == my_label) ? 1 : 0;
    const unsigned mask = (unsigned)__ballot(same_l);

    const f4* semb4 = reinterpret_cast<const f4*>(semb + (size_t)k * B * D);
    f4*       nbr4  = reinterpret_cast<f4*>(nbr + (size_t)kb * TD);
    const f4  a     = reinterpret_cast<const f4*>(semb + (size_t)kb * D)[d4];

    #pragma unroll
    for (int g = 0; g < 2; ++g) {
        int ridx[8];
        #pragma unroll
        for (int j = 0; j < 8; ++j)
            ridx[j] = __shfl(idx_l, 16 * g + 2 * j + half, 64);

        f4 sv[8];
        #pragma unroll
        for (int j = 0; j < 8; ++j)
            sv[j] = semb4[(size_t)ridx[j] * (D / 4) + d4];

        #pragma unroll
        for (int j = 0; j < 8; ++j) {
            const int row = 16 * g + 2 * j + half;
            nbr4[row * (D / 4) + d4] = sv[j];
            const float p = hreduce32(dot4(a, sv[j]));
            if (d4 == 0) w.nsim[row] = p;   // lane0 -> even rows, lane32 -> odd
        }
    }

    if (l < 32) ws_nsim[kb * T + l] = w.nsim[l];
    if (l == 0) ws_mask[kb] = mask;
}

// MODE 0=pos, 1=neg, 2=mask. One contiguous 64MiB stream each.
template<int MODE>
__global__ __launch_bounds__(256) void expand_kernel(
    const float*    __restrict__ nsim,   // [K,B,T]
    const unsigned* __restrict__ maskw,  // [K,B]
    float*          __restrict__ out)    // [K,B,T,T]
{
    const int tid = threadIdx.x;
    const int s   = tid >> 3;
    const int d0  = (tid & 7) * 4;
    f4*       out4  = reinterpret_cast<f4*>(out);
    const f4* nsim4 = reinterpret_cast<const f4*>(nsim);
    const int base_kb = blockIdx.x * 8;

    #pragma unroll
    for (int j = 0; j < 8; ++j) {
        const int kb = base_kb + j;
        const unsigned m  = maskw[kb];
        const int      ss = (m >> s) & 1;
        const unsigned md = (m >> d0) & 0xFu;
        const int m0 = ss & (((md >> 0) & 1) ^ 1);
        const int m1 = ss & (((md >> 1) & 1) ^ 1);
        const int m2 = ss & (((md >> 2) & 1) ^ 1);
        const int m3 = ss & (((md >> 3) & 1) ^ 1);

        f4 v;
        if (MODE == 2) {
            v.x = (float)m0; v.y = (float)m1; v.z = (float)m2; v.w = (float)m3;
        } else if (MODE == 0) {
            const float ps = nsim[kb * T + s];
            v.x = m0 ? ps : 0.0f; v.y = m1 ? ps : 0.0f;
            v.z = m2 ? ps : 0.0f; v.w = m3 ? ps : 0.0f;
        } else {
            const f4 nd = nsim4[kb * (T / 4) + (tid & 7)];
            v.x = m0 ? nd.x : 0.0f; v.y = m1 ? nd.y : 0.0f;
            v.z = m2 ? nd.z : 0.0f; v.w = m3 ? nd.w : 0.0f;
        }
        out4[(size_t)kb * (TT / 4) + tid] = v;
    }
}

// Fallback: monolithic kernel (used only if ws_size is too small).
__global__ __launch_bounds__(256) void distance_layer_kernel(
    const float* __restrict__ semb, const int* __restrict__ slabels,
    const int* __restrict__ topk, float* __restrict__ pos,
    float* __restrict__ neg, float* __restrict__ maskf, float* __restrict__ nbr)
{
    const int tid  = threadIdx.x;
    const int wid  = tid >> 6;
    const int l    = tid & 63;
    const int half = l >> 5;
    const int d4   = l & 31;
    const int kb = blockIdx.x * 4 + wid;
    const int k  = kb >> 12;

    __shared__ WaveSh sh[4];
    WaveSh& w = sh[wid];

    const int my_label = slabels[kb];
    const int idx_l    = topk[kb * T + d4];
    const int same_l   = (slabels[(k << 12) + idx_l] == my_label) ? 1 : 0;
    const unsigned mask = (unsigned)__ballot(same_l);

    const f4* semb4 = reinterpret_cast<const f4*>(semb + (size_t)k * B * D);
    f4*       nbr4  = reinterpret_cast<f4*>(nbr + (size_t)kb * TD);
    const f4  a     = reinterpret_cast<const f4*>(semb + (size_t)kb * D)[d4];

    #pragma unroll
    for (int g = 0; g < 2; ++g) {
        int ridx[8];
        #pragma unroll
        for (int j = 0; j < 8; ++j)
            ridx[j] = __shfl(idx_l, 16 * g + 2 * j + half, 64);
        f4 sv[8];
        #pragma unroll
        for (int j = 0; j < 8; ++j)
            sv[j] = semb4[(size_t)ridx[j] * (D / 4) + d4];
        #pragma unroll
        for (int j = 0; j < 8; ++j) {
            const int row = 16 * g + 2 * j + half;
            nbr4[row * (D / 4) + d4] = sv[j];
            const float p = hreduce32(dot4(a, sv[j]));
            if (d4 == 0) w.nsim[row] = p;
        }
    }

    const int d0 = (l & 7) * 4;
    const f4 ndv = *reinterpret_cast<const f4*>(&w.nsim[d0]);
    const unsigned md = (mask >> d0) & 0xFu;
    const int b0 = md & 1, b1 = (md >> 1) & 1, b2 = (md >> 2) & 1, b3 = (md >> 3) & 1;

    f4* pos4  = reinterpret_cast<f4*>(pos   + (size_t)kb * TT);
    f4* neg4  = reinterpret_cast<f4*>(neg   + (size_t)kb * TT);
    f4* mask4 = reinterpret_cast<f4*>(maskf + (size_t)kb * TT);

    #pragma unroll
    for (int i = 0; i < 4; ++i) {
        const int   s  = 8 * i + (l >> 3);
        const int   ss = (mask >> s) & 1;
        const float ps = w.nsim[s];
        const int m0 = ss & (b0 ^ 1), m1 = ss & (b1 ^ 1);
        const int m2 = ss & (b2 ^ 1), m3 = ss & (b3 ^ 1);
        f4 pv, nv, mv;
        pv.x = m0 ? ps : 0.0f;  nv.x = m0 ? ndv.x : 0.0f;  mv.x = (float)m0;
        pv.y = m1 ? ps : 0.0f;  nv.y = m1 ? ndv.y : 0.0f;  mv.y = (float)m1;
        pv.z = m2 ? ps : 0.0f;  nv.z = m2 ? ndv.z : 0.0f;  mv.z = (float)m2;
        pv.w = m3 ? ps : 0.0f;  nv.w = m3 ? ndv.w : 0.0f;  mv.w = (float)m3;
        pos4 [64 * i + l] = pv;
        neg4 [64 * i + l] = nv;
        mask4[64 * i + l] = mv;
    }
}

extern "C" void kernel_launch(void* const* d_in, const int* in_sizes, int n_in,
                              void* d_out, int out_size, void* d_ws, size_t ws_size,
                              hipStream_t stream) {
    const float* semb    = (const float*)d_in[0];
    const int*   slabels = (const int*)d_in[1];
    const int*   topk    = (const int*)d_in[2];

    float* out = (float*)d_out;
    const size_t KBTT = (size_t)K * B * T * T;   // 16,777,216
    float* pos   = out;
    float* neg   = out + KBTT;
    float* maskf = out + 2 * KBTT;
    float* nbr   = out + 3 * KBTT;

    const size_t NSIM_BYTES = (size_t)K * B * T * sizeof(float);   // 2 MiB
    const size_t MASK_BYTES = (size_t)K * B * sizeof(unsigned);    // 64 KiB

    // PROBE: run the full idempotent pipeline TWICE. Added time == one
    // kernel-pipeline time K, separating K from the fixed harness overhead.
    for (int rep = 0; rep < 2; ++rep) {
        if (ws_size >= NSIM_BYTES + MASK_BYTES) {
            float*    ws_nsim = (float*)d_ws;
            unsigned* ws_mask = (unsigned*)((char*)d_ws + NSIM_BYTES);
            gather_kernel<<<dim3(K * B / 4), dim3(256), 0, stream>>>(
                semb, slabels, topk, nbr, ws_nsim, ws_mask);
            expand_kernel<0><<<dim3(K * B / 8), dim3(256), 0, stream>>>(ws_nsim, ws_mask, pos);
            expand_kernel<1><<<dim3(K * B / 8), dim3(256), 0, stream>>>(ws_nsim, ws_mask, neg);
            expand_kernel<2><<<dim3(K * B / 8), dim3(256), 0, stream>>>(ws_nsim, ws_mask, maskf);
        } else {
            distance_layer_kernel<<<dim3(K * B / 4), dim3(256), 0, stream>>>(
                semb, slabels, topk, pos, neg, maskf, nbr);
        }
    }
}

// Round 5
// 463.036 us; speedup vs baseline: 1.2507x; 1.2507x over previous
//
#include <hip/hip_runtime.h>

// Problem constants (match reference): K=4, B=4096, T=32, D=128
constexpr int K = 4;
constexpr int B = 4096;   // power of two: kb>>12 = k
constexpr int T = 32;
constexpr int D = 128;
constexpr int TT = T * T;   // 1024 pairs per anchor
constexpr int TD = T * D;   // 4096 floats per anchor's nbr_embed

typedef float f4 __attribute__((ext_vector_type(4)));

__device__ __forceinline__ float dot4(f4 a, f4 b) {
    return a.x * b.x + a.y * b.y + a.z * b.z + a.w * b.w;
}

// butterfly sum across each 32-lane half of the wave-64 (xor masks <=16
// never cross the half boundary)
__device__ __forceinline__ float hreduce32(float p) {
    #pragma unroll
    for (int m = 16; m >= 1; m >>= 1) p += __shfl_xor(p, m, 64);
    return p;
}

// 128 B of wave-private LDS per anchor: the only cross-lane exchange that
// can't ride on shfl/ballot. Same-wave LDS is in-order -> no barrier ever.
struct __align__(16) WaveSh { float nsim[T]; };

// ---------------------------------------------------------------------------
// SESSION FINDINGS (R0-R4), measured on MI355X:
//   - Timed region = ~365us FIXED harness overhead (one ~300us 1.9GB output
//     poison fill + ~65us reset/launch-gap micro-dispatches) + kernel K.
//   - K measured directly via idempotent double-run probe (R4): K ~= 107us
//     for the 4-kernel split; monolithic variants are statistically equal.
//   - Structural floor: 470MB mandatory writes (+~30-50MB effective reads)
//     at the 6.3TB/s fill yardstick ~= 80-85us -> K is at ~80% of floor.
//   - Four independent structural theories all NEUTRAL (+-7us): barrier
//     drain (R1), XCD k-affinity for gather L2 locality (R2), write-stream
//     isolation / fillBuffer-shaped expanders (R3), kernel fission (R3).
//     With 365us fixed, remaining kernel headroom (<25us) is <5% of dur.
// This final version: single launch (fewest launch gaps), wave-per-anchor,
// barrier-free. Plain stores (NT measured ~2.2x slower in the prior session).
// ---------------------------------------------------------------------------
__global__ __launch_bounds__(256) void distance_layer_kernel(
    const float* __restrict__ semb,     // [K,B,D]
    const int*   __restrict__ slabels,  // [K,B]
    const int*   __restrict__ topk,     // [K,B,T]
    float* __restrict__ pos,            // [K,B,T,T]
    float* __restrict__ neg,            // [K,B,T,T]
    float* __restrict__ maskf,          // [K,B,T,T] (bool as 0.0/1.0)
    float* __restrict__ nbr)            // [K,B,T,D]
{
    const int tid  = threadIdx.x;
    const int wid  = tid >> 6;          // wave id within block = anchor slot
    const int l    = tid & 63;          // lane
    const int half = l >> 5;            // 0: even rows, 1: odd rows
    const int d4   = l & 31;            // float4 column within the D=128 row

    const int kb = blockIdx.x * 4 + wid;
    const int k  = kb >> 12;

    __shared__ WaveSh sh[4];
    WaveSh& w = sh[wid];

    // ---- wave-local staging: indices + same-label ballot ---------------
    const int my_label = slabels[kb];
    const int idx_l    = topk[kb * T + d4];   // lane l holds idx of row (l&31)
    const int same_l   = (slabels[(k << 12) + idx_l] == my_label) ? 1 : 0;
    // low 32 bits: bit r = same[r] (both halves agree, truncation is safe)
    const unsigned mask = (unsigned)__ballot(same_l);

    const f4* semb4 = reinterpret_cast<const f4*>(semb + (size_t)k * B * D);
    f4*       nbr4  = reinterpret_cast<f4*>(nbr + (size_t)kb * TD);
    const f4  a     = reinterpret_cast<const f4*>(semb + (size_t)kb * D)[d4];

    // ---- gather + nsim: 2 rows per step (one per half), 8-deep MLP -----
    #pragma unroll
    for (int g = 0; g < 2; ++g) {
        int ridx[8];
        #pragma unroll
        for (int j = 0; j < 8; ++j)
            ridx[j] = __shfl(idx_l, 16 * g + 2 * j + half, 64);

        f4 sv[8];
        #pragma unroll
        for (int j = 0; j < 8; ++j)
            sv[j] = semb4[(size_t)ridx[j] * (D / 4) + d4];

        #pragma unroll
        for (int j = 0; j < 8; ++j) {
            const int row = 16 * g + 2 * j + half;
            nbr4[row * (D / 4) + d4] = sv[j];           // fire-and-forget
            const float p = hreduce32(dot4(a, sv[j]));  // full sum in all lanes
            if (d4 == 0) w.nsim[row] = p;               // lane0 -> even, lane32 -> odd
        }
    }

    // ---- pair grid: 1024 (s,d) pairs, 16 per lane as 4x float4 ---------
    // flat pair index = (64*i + l)*4 + j  ->  s = 8i + (l>>3), d = (l&7)*4 + j
    const int d0 = (l & 7) * 4;
    const f4 ndv = *reinterpret_cast<const f4*>(&w.nsim[d0]); // in-wave LDS, ordered
    const unsigned md = (mask >> d0) & 0xFu;
    const int b0 =  md       & 1;
    const int b1 = (md >> 1) & 1;
    const int b2 = (md >> 2) & 1;
    const int b3 = (md >> 3) & 1;

    f4* pos4  = reinterpret_cast<f4*>(pos   + (size_t)kb * TT);
    f4* neg4  = reinterpret_cast<f4*>(neg   + (size_t)kb * TT);
    f4* mask4 = reinterpret_cast<f4*>(maskf + (size_t)kb * TT);

    #pragma unroll
    for (int i = 0; i < 4; ++i) {
        const int   s  = 8 * i + (l >> 3);
        const int   ss = (mask >> s) & 1;
        const float ps = w.nsim[s];

        const int m0 = ss & (b0 ^ 1);
        const int m1 = ss & (b1 ^ 1);
        const int m2 = ss & (b2 ^ 1);
        const int m3 = ss & (b3 ^ 1);

        f4 pv, nv, mv;
        pv.x = m0 ? ps : 0.0f;  nv.x = m0 ? ndv.x : 0.0f;  mv.x = (float)m0;
        pv.y = m1 ? ps : 0.0f;  nv.y = m1 ? ndv.y : 0.0f;  mv.y = (float)m1;
        pv.z = m2 ? ps : 0.0f;  nv.z = m2 ? ndv.z : 0.0f;  mv.z = (float)m2;
        pv.w = m3 ? ps : 0.0f;  nv.w = m3 ? ndv.w : 0.0f;  mv.w = (float)m3;

        pos4 [64 * i + l] = pv;   // contiguous 1KB per wave per instruction
        neg4 [64 * i + l] = nv;
        mask4[64 * i + l] = mv;
    }
}

extern "C" void kernel_launch(void* const* d_in, const int* in_sizes, int n_in,
                              void* d_out, int out_size, void* d_ws, size_t ws_size,
                              hipStream_t stream) {
    const float* semb    = (const float*)d_in[0];
    const int*   slabels = (const int*)d_in[1];
    const int*   topk    = (const int*)d_in[2];

    float* out = (float*)d_out;
    const size_t KBTT = (size_t)K * B * T * T;   // 16,777,216
    float* pos   = out;
    float* neg   = out + KBTT;
    float* maskf = out + 2 * KBTT;
    float* nbr   = out + 3 * KBTT;

    distance_layer_kernel<<<dim3(K * B / 4), dim3(256), 0, stream>>>(
        semb, slabels, topk, pos, neg, maskf, nbr);
}